// Round 12
// baseline (728.162 us; speedup 1.0000x reference)
//
#include <hip/hip_runtime.h>
#include <hip/hip_bf16.h>

#define T_STEPS 365
#define XLEN    (T_STEPS * 3)
#define H_SZ    256
#define ROWS    16
#define NW      8      // waves per block (2 per SIMD)
#define CPW     32     // state cols per wave

#define SF1     (-1.4426950408889634f)   // -log2(e): folded into W_f, W_o
#define SF2     (-2.8853900817779268f)   // -2 log2(e): folded into W_g, tanh(c)

typedef __attribute__((ext_vector_type(8))) short bf16x8;   // 8 bf16 = 4 VGPRs
typedef __attribute__((ext_vector_type(4))) short bf16x4;   // 4 bf16 = 2 VGPRs
typedef __attribute__((ext_vector_type(4))) float f32x4;

__device__ __forceinline__ float fast_sigmoid(float x) {    // plain form (iv only)
    return __builtin_amdgcn_rcpf(1.0f + __builtin_amdgcn_exp2f(-1.44269504f * x));
}
__device__ __forceinline__ unsigned short f2bf(float x) {   // fp32 -> bf16 RTNE
    __hip_bfloat16 b = __float2bfloat16(x);
    return *reinterpret_cast<unsigned short*>(&b);
}
__device__ __forceinline__ float bf2f(unsigned short v) {
    return __uint_as_float(((unsigned)v) << 16);
}
__device__ __forceinline__ bf16x8 expand4(bf16x4 v) {       // {v0..v3,0,0,0,0}
    bf16x8 r = (bf16x8)0;
    r[0] = v[0]; r[1] = v[1]; r[2] = v[2]; r[3] = v[3];
    return r;
}
// exp2-native LSTM gate bundle (weights pre-scaled by SF1/SF2)
__device__ __forceinline__ bf16x4 do_gates(const f32x4 zf, const f32x4 zg,
                                           const f32x4 zo, const float iv[4],
                                           float cst[4]) {
    bf16x4 pk;
#pragma unroll
    for (int q = 0; q < 4; ++q) {
        const float fq = __builtin_amdgcn_rcpf(1.0f + __builtin_amdgcn_exp2f(zf[q]));
        const float gq = 2.0f * __builtin_amdgcn_rcpf(1.0f + __builtin_amdgcn_exp2f(zg[q])) - 1.0f;
        const float oq = __builtin_amdgcn_rcpf(1.0f + __builtin_amdgcn_exp2f(zo[q]));
        const float cq = fq * cst[q] + iv[q] * gq;
        cst[q] = cq;
        const float th = 2.0f * __builtin_amdgcn_rcpf(1.0f + __builtin_amdgcn_exp2f(SF2 * cq)) - 1.0f;
        pk[q] = (short)f2bf(oq * th);
    }
    return pk;
}

// pre-kernel: pack x_dyn -> d_ws as bf16 {x0,x1,x2,1.0} per (block,t,row)
__global__ void __launch_bounds__(256)
xstage(const float* __restrict__ x_dyn, unsigned short* __restrict__ xg)
{
    const int rb = blockIdx.x * ROWS;
    for (int idx = threadIdx.x; idx < T_STEPS * ROWS; idx += 256) {
        const int t = idx % T_STEPS, r = idx / T_STEPS;
        const float* s = x_dyn + (size_t)(rb + r) * XLEN + t * 3;
        bf16x4 pk;
        pk[0] = (short)f2bf(s[0]); pk[1] = (short)f2bf(s[1]);
        pk[2] = (short)f2bf(s[2]); pk[3] = (short)0x3F80;   // 1.0 bf16
        *(bf16x4*)&xg[((size_t)blockIdx.x * T_STEPS + t) * 64 + r * 4] = pk;
    }
}

// Round-12: producer/consumer wave roles with PARITY pairing + setprio.
// grpA = even waves (own kt {0,2,4,6}); grpB = odd waves (own kt {1,3,5,7}).
// If HW maps consecutive wave pairs to a SIMD (w/2), each SIMD hosts 1A+1B ->
// cross-wave MFMA/trans co-issue. s_setprio(1) biases MFMA clusters (T5).
// seg1: A: MFMA even-kt(t)            | B: deferred gates(t-1), write odd cols
// bar_a
// seg2: A: MFMA odd-kt + x, gates(t)  | B: MFMA all kt + x -> accB (deferred)
// bar_b
__global__ void __launch_bounds__(512, 2)
ealstm_fused(const unsigned short* __restrict__ xg, const float* __restrict__ x_stat,
             const float* __restrict__ w_i, const float* __restrict__ b_i,
             const float* __restrict__ w_f, const float* __restrict__ b_f,
             const float* __restrict__ w_g, const float* __restrict__ b_g,
             const float* __restrict__ w_o, const float* __restrict__ b_o,
             const float* __restrict__ w_head, const float* __restrict__ b_head,
             float* __restrict__ out)
{
    const int tid   = threadIdx.x;
    const int lane  = tid & 63;
    const int wv    = tid >> 6;       // 0..7
    const int m     = lane & 15;      // batch row (N dim of D)
    const int l16   = lane >> 4;      // 0..3
    const int rb    = blockIdx.x * ROWS;
    const int wbase = wv * CPW;
    const bool grpA = ((wv & 1) == 0);

    __shared__ unsigned short wo_lds[4 * 8 * 256 * 8];    // 128 KB [l16][kt][c][e]
    __shared__ unsigned short hbuf[2][4096];              // 16 KB h^T B-pack, dbuf
    __shared__ float          red[NW][ROWS];

    // ---- one-time staging ----
    for (int idx = tid; idx < 4 * 8 * 8 * 256; idx += 512) {
        const int c    = idx & 255;
        const int e    = (idx >> 8) & 7;
        const int kt   = (idx >> 11) & 7;
        const int l16g = idx >> 14;
        wo_lds[((l16g * 8 + kt) * 256 + c) * 8 + e] =
            f2bf(SF1 * w_o[(3 + kt * 32 + l16g * 8 + e) * H_SZ + c]);
    }
    for (int idx = tid; idx < 2048; idx += 512) ((unsigned int*)hbuf[0])[idx] = 0u;

    const float* wsrc[3] = {w_f, w_g, w_o};
    const float* bsrc[3] = {b_f, b_g, b_o};
    const float  gsf[3]  = {SF1, SF2, SF1};

    // ---- weights -> registers (pre-scaled) ----
    bf16x8 wA[8][2][2];      // f,g gates, all 8 kt = 128 regs
    bf16x4 wX[2][3];         // x/bias tile; nonzero only l16==0
#pragma unroll
    for (int ct = 0; ct < 2; ++ct) {
        const int c = wbase + ct * 16 + m;
#pragma unroll
        for (int g = 0; g < 2; ++g)
#pragma unroll
            for (int kt = 0; kt < 8; ++kt) {
                bf16x8 a;
#pragma unroll
                for (int e = 0; e < 8; ++e)
                    a[e] = (short)f2bf(gsf[g] * wsrc[g][(3 + kt * 32 + l16 * 8 + e) * H_SZ + c]);
                wA[kt][ct][g] = a;
            }
#pragma unroll
        for (int g = 0; g < 3; ++g) {
            bf16x4 ax = (bf16x4)0;
            if (l16 == 0) {
                ax[0] = (short)f2bf(gsf[g] * wsrc[g][0 * H_SZ + c]);
                ax[1] = (short)f2bf(gsf[g] * wsrc[g][1 * H_SZ + c]);
                ax[2] = (short)f2bf(gsf[g] * wsrc[g][2 * H_SZ + c]);
                ax[3] = (short)f2bf(gsf[g] * bsrc[g][c]);
            }
            wX[ct][g] = ax;
        }
    }

    // ---- static input gate (fp32 regs) + cell state ----
    float iv[2][4], cst[2][4];
    {
        const float xs0 = x_stat[(rb + m) * 3 + 0];
        const float xs1 = x_stat[(rb + m) * 3 + 1];
        const float xs2 = x_stat[(rb + m) * 3 + 2];
#pragma unroll
        for (int ct = 0; ct < 2; ++ct)
#pragma unroll
            for (int q = 0; q < 4; ++q) {
                const int c = wbase + ct * 16 + l16 * 4 + q;
                iv[ct][q] = fast_sigmoid(b_i[c] + xs0 * w_i[c] + xs1 * w_i[H_SZ + c]
                                                + xs2 * w_i[2 * H_SZ + c]);
                cst[ct][q] = 0.0f;
            }
    }

    // h-write offsets: c0 = wbase+ct*16+l16*4; kt=c0>>5; L=m+16*((c0&31)>>3); e=c0&7
    int woff[2];
#pragma unroll
    for (int ct = 0; ct < 2; ++ct) {
        const int c0 = wbase + ct * 16 + l16 * 4;
        woff[ct] = ((c0 >> 5) * 64 + m + 16 * ((c0 & 31) >> 3)) * 8 + (c0 & 7);
    }

    const unsigned short* xrow   = xg + (size_t)blockIdx.x * T_STEPS * 64 + m * 4;
    const bf16x8*         wobase = (const bf16x8*)&wo_lds[((l16 * 8) * 256 + wbase + m) * 8];

    f32x4 accB[2][3];   // B-group: acc carried across bar_b into next seg1

    __syncthreads();

    for (int t = 0; t < T_STEPS; ++t) {
        const bf16x8* hp = (const bf16x8*)hbuf[t & 1] + lane;   // h(t-1)
        unsigned short* hwW = hbuf[(t + 1) & 1];                // h(t) slot
        unsigned short* hwP = hbuf[t & 1];                      // h(t-1) slot (B late-write)

        // x(t) B-frag — hoisted above the role branch (early global load)
        bf16x8 xf = (bf16x8)0;
        {
            unsigned long long xv = *(const unsigned long long*)&xrow[(size_t)t * 64];
            if (l16 != 0) xv = 0ULL;
            union { unsigned long long u; bf16x4 v; } X; X.u = xv;
            xf[0] = X.v[0]; xf[1] = X.v[1]; xf[2] = X.v[2]; xf[3] = X.v[3];
        }

        f32x4 accA[2][3];

        // ================= seg1 =================
        if (grpA) {
            // MFMA even kt (A-owned cols of h(t-1), written in prev seg2)
            const f32x4 z4 = {0.f, 0.f, 0.f, 0.f};
            __builtin_amdgcn_s_setprio(1);
            {
                const bf16x8 b = hp[0];
#pragma unroll
                for (int ct = 0; ct < 2; ++ct) {
                    accA[ct][0] = __builtin_amdgcn_mfma_f32_16x16x32_bf16(wA[0][ct][0], b, z4, 0, 0, 0);
                    accA[ct][1] = __builtin_amdgcn_mfma_f32_16x16x32_bf16(wA[0][ct][1], b, z4, 0, 0, 0);
                    accA[ct][2] = __builtin_amdgcn_mfma_f32_16x16x32_bf16(wobase[ct * 16], b, z4, 0, 0, 0);
                }
            }
#pragma unroll
            for (int kt = 2; kt < 8; kt += 2) {
                const bf16x8 b = hp[kt * 64];
#pragma unroll
                for (int ct = 0; ct < 2; ++ct) {
                    accA[ct][0] = __builtin_amdgcn_mfma_f32_16x16x32_bf16(wA[kt][ct][0], b, accA[ct][0], 0, 0, 0);
                    accA[ct][1] = __builtin_amdgcn_mfma_f32_16x16x32_bf16(wA[kt][ct][1], b, accA[ct][1], 0, 0, 0);
                    accA[ct][2] = __builtin_amdgcn_mfma_f32_16x16x32_bf16(wobase[kt * 256 + ct * 16], b, accA[ct][2], 0, 0, 0);
                }
            }
            __builtin_amdgcn_s_setprio(0);
        } else {
            if (t > 0) {   // deferred gates for step t-1; write own (odd-kt) cols
                const bf16x4 pk0 = do_gates(accB[0][0], accB[0][1], accB[0][2], iv[0], cst[0]);
                *(bf16x4*)&hwP[woff[0]] = pk0;
                const bf16x4 pk1 = do_gates(accB[1][0], accB[1][1], accB[1][2], iv[1], cst[1]);
                *(bf16x4*)&hwP[woff[1]] = pk1;
            }
        }
        __syncthreads();   // bar_a: odd-kt cols of h(t-1) visible

        // ================= seg2 =================
        if (grpA) {
            __builtin_amdgcn_s_setprio(1);
#pragma unroll
            for (int kt = 1; kt < 8; kt += 2) {
                const bf16x8 b = hp[kt * 64];
#pragma unroll
                for (int ct = 0; ct < 2; ++ct) {
                    accA[ct][0] = __builtin_amdgcn_mfma_f32_16x16x32_bf16(wA[kt][ct][0], b, accA[ct][0], 0, 0, 0);
                    accA[ct][1] = __builtin_amdgcn_mfma_f32_16x16x32_bf16(wA[kt][ct][1], b, accA[ct][1], 0, 0, 0);
                    accA[ct][2] = __builtin_amdgcn_mfma_f32_16x16x32_bf16(wobase[kt * 256 + ct * 16], b, accA[ct][2], 0, 0, 0);
                }
            }
#pragma unroll
            for (int ct = 0; ct < 2; ++ct)
#pragma unroll
                for (int g = 0; g < 3; ++g)
                    accA[ct][g] = __builtin_amdgcn_mfma_f32_16x16x32_bf16(
                        expand4(wX[ct][g]), xf, accA[ct][g], 0, 0, 0);
            __builtin_amdgcn_s_setprio(0);
            const bf16x4 pk0 = do_gates(accA[0][0], accA[0][1], accA[0][2], iv[0], cst[0]);
            *(bf16x4*)&hwW[woff[0]] = pk0;
            const bf16x4 pk1 = do_gates(accA[1][0], accA[1][1], accA[1][2], iv[1], cst[1]);
            *(bf16x4*)&hwW[woff[1]] = pk1;
        } else {
            const f32x4 z4 = {0.f, 0.f, 0.f, 0.f};
            __builtin_amdgcn_s_setprio(1);
            {
                const bf16x8 b = hp[0];
#pragma unroll
                for (int ct = 0; ct < 2; ++ct) {
                    accB[ct][0] = __builtin_amdgcn_mfma_f32_16x16x32_bf16(wA[0][ct][0], b, z4, 0, 0, 0);
                    accB[ct][1] = __builtin_amdgcn_mfma_f32_16x16x32_bf16(wA[0][ct][1], b, z4, 0, 0, 0);
                    accB[ct][2] = __builtin_amdgcn_mfma_f32_16x16x32_bf16(wobase[ct * 16], b, z4, 0, 0, 0);
                }
            }
#pragma unroll
            for (int kt = 1; kt < 8; ++kt) {
                const bf16x8 b = hp[kt * 64];
#pragma unroll
                for (int ct = 0; ct < 2; ++ct) {
                    accB[ct][0] = __builtin_amdgcn_mfma_f32_16x16x32_bf16(wA[kt][ct][0], b, accB[ct][0], 0, 0, 0);
                    accB[ct][1] = __builtin_amdgcn_mfma_f32_16x16x32_bf16(wA[kt][ct][1], b, accB[ct][1], 0, 0, 0);
                    accB[ct][2] = __builtin_amdgcn_mfma_f32_16x16x32_bf16(wobase[kt * 256 + ct * 16], b, accB[ct][2], 0, 0, 0);
                }
            }
#pragma unroll
            for (int ct = 0; ct < 2; ++ct)
#pragma unroll
                for (int g = 0; g < 3; ++g)
                    accB[ct][g] = __builtin_amdgcn_mfma_f32_16x16x32_bf16(
                        expand4(wX[ct][g]), xf, accB[ct][g], 0, 0, 0);
            __builtin_amdgcn_s_setprio(0);
        }
        __syncthreads();   // bar_b: A-owned (even-kt) cols of h(t) visible
    }

    // ---- epilogue: B flushes gates(T-1) into h slot 1 ----
    if (!grpA) {
        const bf16x4 pk0 = do_gates(accB[0][0], accB[0][1], accB[0][2], iv[0], cst[0]);
        *(bf16x4*)&hbuf[1][woff[0]] = pk0;
        const bf16x4 pk1 = do_gates(accB[1][0], accB[1][1], accB[1][2], iv[1], cst[1]);
        *(bf16x4*)&hbuf[1][woff[1]] = pk1;
    }
    __syncthreads();

    // ---- head: out[r] = sum_c h[r][c] w_head[c] + b_head ----
    float p = 0.0f;
    const unsigned short* hf = hbuf[1];   // h(364) slot = (365)&1 = 1
#pragma unroll
    for (int ct = 0; ct < 2; ++ct) {
        const int c0 = wbase + ct * 16 + l16 * 4;
        const f32x4 wh = *(const f32x4*)&w_head[c0];
        const bf16x4 hv = *(const bf16x4*)&hf[woff[ct]];
#pragma unroll
        for (int q = 0; q < 4; ++q) p += bf2f((unsigned short)hv[q]) * wh[q];
    }
    p += __shfl_xor(p, 16);
    p += __shfl_xor(p, 32);
    if (lane < 16) red[wv][m] = p;
    __syncthreads();
    if (tid < ROWS) {
        float s = b_head[0];
#pragma unroll
        for (int w = 0; w < NW; ++w) s += red[w][tid];
        out[rb + tid] = s;
    }
}

extern "C" void kernel_launch(void* const* d_in, const int* in_sizes, int n_in,
                              void* d_out, int out_size, void* d_ws, size_t ws_size,
                              hipStream_t stream)
{
    const float* x_dyn  = (const float*)d_in[0];
    const float* x_stat = (const float*)d_in[1];
    const float* w_i    = (const float*)d_in[2];
    const float* b_i    = (const float*)d_in[3];
    const float* w_f    = (const float*)d_in[4];
    const float* b_f    = (const float*)d_in[5];
    const float* w_g    = (const float*)d_in[6];
    const float* b_g    = (const float*)d_in[7];
    const float* w_o    = (const float*)d_in[8];
    const float* b_o    = (const float*)d_in[9];
    const float* w_head = (const float*)d_in[10];
    const float* b_head = (const float*)d_in[11];

    unsigned short* xg = (unsigned short*)d_ws;   // 64*365*64*2 B = 2.99 MB

    xstage<<<dim3(64), dim3(256), 0, stream>>>(x_dyn, xg);
    ealstm_fused<<<dim3(64), dim3(512), 0, stream>>>(
        xg, x_stat, w_i, b_i, w_f, b_f, w_g, b_g, w_o, b_o,
        w_head, b_head, (float*)d_out);
}

// Round 13
// 589.499 us; speedup vs baseline: 1.2352x; 1.2352x over previous
//
#include <hip/hip_runtime.h>
#include <hip/hip_bf16.h>

#define T_STEPS 365
#define XLEN    (T_STEPS * 3)
#define H_SZ    256
#define ROWS    16
#define NW      8      // waves per block (2 per SIMD)
#define CPW     32     // state cols per wave

#define SF1     (-1.4426950408889634f)   // -log2(e): folded into W_f, W_o
#define SF2     (-2.8853900817779268f)   // -2 log2(e): folded into W_g, tanh(c)

typedef __attribute__((ext_vector_type(8))) short bf16x8;   // 8 bf16 = 4 VGPRs
typedef __attribute__((ext_vector_type(4))) short bf16x4;   // 4 bf16 = 2 VGPRs
typedef __attribute__((ext_vector_type(4))) float f32x4;

__device__ __forceinline__ float fast_sigmoid(float x) {    // plain form (iv only)
    return __builtin_amdgcn_rcpf(1.0f + __builtin_amdgcn_exp2f(-1.44269504f * x));
}
__device__ __forceinline__ unsigned short f2bf(float x) {   // fp32 -> bf16 RTNE
    __hip_bfloat16 b = __float2bfloat16(x);
    return *reinterpret_cast<unsigned short*>(&b);
}
__device__ __forceinline__ float bf2f(unsigned short v) {
    return __uint_as_float(((unsigned)v) << 16);
}
__device__ __forceinline__ bf16x8 expand4(bf16x4 v) {       // {v0..v3,0,0,0,0}
    bf16x8 r = (bf16x8)0;
    r[0] = v[0]; r[1] = v[1]; r[2] = v[2]; r[3] = v[3];
    return r;
}

// pre-kernel: pack x_dyn -> d_ws as bf16 {x0,x1,x2,1.0} per (block,t,row)
__global__ void __launch_bounds__(256)
xstage(const float* __restrict__ x_dyn, unsigned short* __restrict__ xg)
{
    const int rb = blockIdx.x * ROWS;
    for (int idx = threadIdx.x; idx < T_STEPS * ROWS; idx += 256) {
        const int t = idx % T_STEPS, r = idx / T_STEPS;
        const float* s = x_dyn + (size_t)(rb + r) * XLEN + t * 3;
        bf16x4 pk;
        pk[0] = (short)f2bf(s[0]); pk[1] = (short)f2bf(s[1]);
        pk[2] = (short)f2bf(s[2]); pk[3] = (short)0x3F80;   // 1.0 bf16
        *(bf16x4*)&xg[((size_t)blockIdx.x * T_STEPS + t) * 64 + r * 4] = pk;
    }
}

// Round-13 = Round-10 structure (best, 569 us) + x-latency pipeline:
//   * x(t+1) prefetched into regs at top of step t (full step body hides
//     the global/HBM latency; conservative pre-barrier vmcnt(0) otherwise
//     exposes ~200-900 cyc at the first x-tile MFMA every step).
//   * x-tile MFMAs moved to END of each acc chain (kt0 inits from zero).
// Everything else identical to round 10.
__global__ void __launch_bounds__(512, 2)
ealstm_fused(const unsigned short* __restrict__ xg, const float* __restrict__ x_stat,
             const float* __restrict__ w_i, const float* __restrict__ b_i,
             const float* __restrict__ w_f, const float* __restrict__ b_f,
             const float* __restrict__ w_g, const float* __restrict__ b_g,
             const float* __restrict__ w_o, const float* __restrict__ b_o,
             const float* __restrict__ w_head, const float* __restrict__ b_head,
             float* __restrict__ out)
{
    const int tid   = threadIdx.x;
    const int lane  = tid & 63;
    const int wv    = tid >> 6;       // 0..7
    const int m     = lane & 15;      // batch row (N dim of D)
    const int l16   = lane >> 4;      // 0..3
    const int rb    = blockIdx.x * ROWS;
    const int wbase = wv * CPW;

    __shared__ unsigned short wo_lds[4 * 8 * 256 * 8];    // 128 KB [l16][kt][c][e]
    __shared__ unsigned short hbuf[2][4096];              // 16 KB h^T B-pack, dbuf
    __shared__ float          red[NW][ROWS];

    // ---- one-time staging ----
    for (int idx = tid; idx < 4 * 8 * 8 * 256; idx += 512) {
        const int c    = idx & 255;
        const int e    = (idx >> 8) & 7;
        const int kt   = (idx >> 11) & 7;
        const int l16g = idx >> 14;
        wo_lds[((l16g * 8 + kt) * 256 + c) * 8 + e] =
            f2bf(SF1 * w_o[(3 + kt * 32 + l16g * 8 + e) * H_SZ + c]);
    }
    for (int idx = tid; idx < 2048; idx += 512) ((unsigned int*)hbuf[0])[idx] = 0u;

    const float* wsrc[3] = {w_f, w_g, w_o};
    const float* bsrc[3] = {b_f, b_g, b_o};
    const float  gsf[3]  = {SF1, SF2, SF1};

    // ---- weights -> registers (pre-scaled) ----
    bf16x8 wA[8][2][2];      // f,g gates, all 8 kt = 128 regs (AGPR side)
    bf16x4 wX[2][3];         // x/bias tile, 12 regs; nonzero only l16==0
#pragma unroll
    for (int ct = 0; ct < 2; ++ct) {
        const int c = wbase + ct * 16 + m;
#pragma unroll
        for (int g = 0; g < 2; ++g)
#pragma unroll
            for (int kt = 0; kt < 8; ++kt) {
                bf16x8 a;
#pragma unroll
                for (int e = 0; e < 8; ++e)
                    a[e] = (short)f2bf(gsf[g] * wsrc[g][(3 + kt * 32 + l16 * 8 + e) * H_SZ + c]);
                wA[kt][ct][g] = a;
            }
#pragma unroll
        for (int g = 0; g < 3; ++g) {
            bf16x4 ax = (bf16x4)0;
            if (l16 == 0) {
                ax[0] = (short)f2bf(gsf[g] * wsrc[g][0 * H_SZ + c]);
                ax[1] = (short)f2bf(gsf[g] * wsrc[g][1 * H_SZ + c]);
                ax[2] = (short)f2bf(gsf[g] * wsrc[g][2 * H_SZ + c]);
                ax[3] = (short)f2bf(gsf[g] * bsrc[g][c]);
            }
            wX[ct][g] = ax;
        }
    }

    // ---- static input gate (fp32 regs) + cell state ----
    float iv[2][4], cst[2][4];
    {
        const float xs0 = x_stat[(rb + m) * 3 + 0];
        const float xs1 = x_stat[(rb + m) * 3 + 1];
        const float xs2 = x_stat[(rb + m) * 3 + 2];
#pragma unroll
        for (int ct = 0; ct < 2; ++ct)
#pragma unroll
            for (int q = 0; q < 4; ++q) {
                const int c = wbase + ct * 16 + l16 * 4 + q;
                iv[ct][q] = fast_sigmoid(b_i[c] + xs0 * w_i[c] + xs1 * w_i[H_SZ + c]
                                                + xs2 * w_i[2 * H_SZ + c]);
                cst[ct][q] = 0.0f;
            }
    }

    // h-write offsets: c0 = wbase+ct*16+l16*4; kt=c0>>5; L=m+16*((c0&31)>>3); e=c0&7
    int woff[2];
#pragma unroll
    for (int ct = 0; ct < 2; ++ct) {
        const int c0 = wbase + ct * 16 + l16 * 4;
        woff[ct] = ((c0 >> 5) * 64 + m + 16 * ((c0 & 31) >> 3)) * 8 + (c0 & 7);
    }

    // loop-invariant base pointers
    const unsigned short* xrow   = xg + (size_t)blockIdx.x * T_STEPS * 64 + m * 4;
    const bf16x8*         wobase = (const bf16x8*)&wo_lds[((l16 * 8) * 256 + wbase + m) * 8];

    __syncthreads();

    // ---- x prefetch pipeline: xv_cur holds x(t) at top of step t ----
    unsigned long long xv_cur = *(const unsigned long long*)&xrow[0];

    for (int t = 0; t < T_STEPS; ++t) {
        const int cur = t & 1;
        const bf16x8* hp = (const bf16x8*)hbuf[cur] + lane;
        unsigned short* hw = hbuf[cur ^ 1];

        // prefetch x(t+1) — full step body hides the latency
        const int tn = (t < T_STEPS - 1) ? t + 1 : t;
        const unsigned long long xv_next =
            *(const unsigned long long*)&xrow[(size_t)tn * 64];

        // build xf from xv_cur (data already resident since last step)
        bf16x8 xf = (bf16x8)0;
        {
            unsigned long long xv = xv_cur;
            if (l16 != 0) xv = 0ULL;
            union { unsigned long long u; bf16x4 v; } X; X.u = xv;
            xf[0] = X.v[0]; xf[1] = X.v[1]; xf[2] = X.v[2]; xf[3] = X.v[3];
        }
        bf16x8 hb[8];
#pragma unroll
        for (int kt = 0; kt < 8; ++kt) hb[kt] = hp[kt * 64];

        f32x4 acc[2][3];
        const f32x4 z4 = {0.f, 0.f, 0.f, 0.f};

        // ================= ct = 0: kt chains (z4 init) + x-tile at end =======
        {
            const bf16x8 wo0 = wobase[0];
            acc[0][0] = __builtin_amdgcn_mfma_f32_16x16x32_bf16(wA[0][0][0], hb[0], z4, 0, 0, 0);
            acc[0][1] = __builtin_amdgcn_mfma_f32_16x16x32_bf16(wA[0][0][1], hb[0], z4, 0, 0, 0);
            acc[0][2] = __builtin_amdgcn_mfma_f32_16x16x32_bf16(wo0,         hb[0], z4, 0, 0, 0);
        }
#pragma unroll
        for (int kt = 1; kt < 8; ++kt) {
            const bf16x8 wo0 = wobase[kt * 256];                 // imm kt*4096
            acc[0][0] = __builtin_amdgcn_mfma_f32_16x16x32_bf16(wA[kt][0][0], hb[kt], acc[0][0], 0, 0, 0);
            acc[0][1] = __builtin_amdgcn_mfma_f32_16x16x32_bf16(wA[kt][0][1], hb[kt], acc[0][1], 0, 0, 0);
            acc[0][2] = __builtin_amdgcn_mfma_f32_16x16x32_bf16(wo0,          hb[kt], acc[0][2], 0, 0, 0);
        }
#pragma unroll
        for (int g = 0; g < 3; ++g)
            acc[0][g] = __builtin_amdgcn_mfma_f32_16x16x32_bf16(
                expand4(wX[0][g]), xf, acc[0][g], 0, 0, 0);
        {   // gates ct0 (exp2-native) + early h-write
            bf16x4 pk;
#pragma unroll
            for (int q = 0; q < 4; ++q) {
                const float fq = __builtin_amdgcn_rcpf(1.0f + __builtin_amdgcn_exp2f(acc[0][0][q]));
                const float gq = 2.0f * __builtin_amdgcn_rcpf(1.0f + __builtin_amdgcn_exp2f(acc[0][1][q])) - 1.0f;
                const float oq = __builtin_amdgcn_rcpf(1.0f + __builtin_amdgcn_exp2f(acc[0][2][q]));
                const float cq = fq * cst[0][q] + iv[0][q] * gq;
                cst[0][q] = cq;
                const float th = 2.0f * __builtin_amdgcn_rcpf(1.0f + __builtin_amdgcn_exp2f(SF2 * cq)) - 1.0f;
                pk[q] = (short)f2bf(oq * th);
            }
            *(bf16x4*)&hw[woff[0]] = pk;
        }

        // ================= ct = 1 ============================================
        {
            const bf16x8 wo1 = wobase[16];
            acc[1][0] = __builtin_amdgcn_mfma_f32_16x16x32_bf16(wA[0][1][0], hb[0], z4, 0, 0, 0);
            acc[1][1] = __builtin_amdgcn_mfma_f32_16x16x32_bf16(wA[0][1][1], hb[0], z4, 0, 0, 0);
            acc[1][2] = __builtin_amdgcn_mfma_f32_16x16x32_bf16(wo1,         hb[0], z4, 0, 0, 0);
        }
#pragma unroll
        for (int kt = 1; kt < 8; ++kt) {
            const bf16x8 wo1 = wobase[kt * 256 + 16];            // imm kt*4096+256
            acc[1][0] = __builtin_amdgcn_mfma_f32_16x16x32_bf16(wA[kt][1][0], hb[kt], acc[1][0], 0, 0, 0);
            acc[1][1] = __builtin_amdgcn_mfma_f32_16x16x32_bf16(wA[kt][1][1], hb[kt], acc[1][1], 0, 0, 0);
            acc[1][2] = __builtin_amdgcn_mfma_f32_16x16x32_bf16(wo1,          hb[kt], acc[1][2], 0, 0, 0);
        }
#pragma unroll
        for (int g = 0; g < 3; ++g)
            acc[1][g] = __builtin_amdgcn_mfma_f32_16x16x32_bf16(
                expand4(wX[1][g]), xf, acc[1][g], 0, 0, 0);
        {
            bf16x4 pk;
#pragma unroll
            for (int q = 0; q < 4; ++q) {
                const float fq = __builtin_amdgcn_rcpf(1.0f + __builtin_amdgcn_exp2f(acc[1][0][q]));
                const float gq = 2.0f * __builtin_amdgcn_rcpf(1.0f + __builtin_amdgcn_exp2f(acc[1][1][q])) - 1.0f;
                const float oq = __builtin_amdgcn_rcpf(1.0f + __builtin_amdgcn_exp2f(acc[1][2][q]));
                const float cq = fq * cst[1][q] + iv[1][q] * gq;
                cst[1][q] = cq;
                const float th = 2.0f * __builtin_amdgcn_rcpf(1.0f + __builtin_amdgcn_exp2f(SF2 * cq)) - 1.0f;
                pk[q] = (short)f2bf(oq * th);
            }
            *(bf16x4*)&hw[woff[1]] = pk;
        }
        xv_cur = xv_next;
        __syncthreads();
    }

    // ---- head: out[r] = sum_c h[r][c] w_head[c] + b_head ----
    float p = 0.0f;
    const unsigned short* hf = hbuf[1];   // t=364: cur=0, wrote hbuf[1]
#pragma unroll
    for (int ct = 0; ct < 2; ++ct) {
        const int c0 = wbase + ct * 16 + l16 * 4;
        const f32x4 wh = *(const f32x4*)&w_head[c0];
        const bf16x4 hv = *(const bf16x4*)&hf[woff[ct]];
#pragma unroll
        for (int q = 0; q < 4; ++q) p += bf2f((unsigned short)hv[q]) * wh[q];
    }
    p += __shfl_xor(p, 16);
    p += __shfl_xor(p, 32);
    if (lane < 16) red[wv][m] = p;
    __syncthreads();
    if (tid < ROWS) {
        float s = b_head[0];
#pragma unroll
        for (int w = 0; w < NW; ++w) s += red[w][tid];
        out[rb + tid] = s;
    }
}

extern "C" void kernel_launch(void* const* d_in, const int* in_sizes, int n_in,
                              void* d_out, int out_size, void* d_ws, size_t ws_size,
                              hipStream_t stream)
{
    const float* x_dyn  = (const float*)d_in[0];
    const float* x_stat = (const float*)d_in[1];
    const float* w_i    = (const float*)d_in[2];
    const float* b_i    = (const float*)d_in[3];
    const float* w_f    = (const float*)d_in[4];
    const float* b_f    = (const float*)d_in[5];
    const float* w_g    = (const float*)d_in[6];
    const float* b_g    = (const float*)d_in[7];
    const float* w_o    = (const float*)d_in[8];
    const float* b_o    = (const float*)d_in[9];
    const float* w_head = (const float*)d_in[10];
    const float* b_head = (const float*)d_in[11];

    unsigned short* xg = (unsigned short*)d_ws;   // 64*365*64*2 B = 2.99 MB

    xstage<<<dim3(64), dim3(256), 0, stream>>>(x_dyn, xg);
    ealstm_fused<<<dim3(64), dim3(512), 0, stream>>>(
        xg, x_stat, w_i, b_i, w_f, b_f, w_g, b_g, w_o, b_o,
        w_head, b_head, (float*)d_out);
}

// Round 14
// 578.138 us; speedup vs baseline: 1.2595x; 1.0197x over previous
//
#include <hip/hip_runtime.h>
#include <hip/hip_bf16.h>

#define T_STEPS 365
#define XLEN    (T_STEPS * 3)
#define H_SZ    256
#define ROWS    16
#define NW      8      // waves per block (2 per SIMD)
#define CPW     32     // state cols per wave

#define SF1     (-1.4426950408889634f)   // -log2(e): folded into W_f, W_o
#define SF2     (-2.8853900817779268f)   // -2 log2(e): folded into W_g, tanh(c)

typedef __attribute__((ext_vector_type(8))) short bf16x8;   // 8 bf16 = 4 VGPRs
typedef __attribute__((ext_vector_type(4))) short bf16x4;   // 4 bf16 = 2 VGPRs
typedef __attribute__((ext_vector_type(4))) float f32x4;

__device__ __forceinline__ float fast_sigmoid(float x) {    // plain form (iv only)
    return __builtin_amdgcn_rcpf(1.0f + __builtin_amdgcn_exp2f(-1.44269504f * x));
}
__device__ __forceinline__ unsigned short f2bf(float x) {   // fp32 -> bf16 RTNE
    __hip_bfloat16 b = __float2bfloat16(x);
    return *reinterpret_cast<unsigned short*>(&b);
}
__device__ __forceinline__ float bf2f(unsigned short v) {
    return __uint_as_float(((unsigned)v) << 16);
}
__device__ __forceinline__ bf16x8 expand4(bf16x4 v) {       // {v0..v3,0,0,0,0}
    bf16x8 r = (bf16x8)0;
    r[0] = v[0]; r[1] = v[1]; r[2] = v[2]; r[3] = v[3];
    return r;
}

// pre-kernel: pack x_dyn -> d_ws as bf16 {x0,x1,x2,1.0} per (block,t,row)
__global__ void __launch_bounds__(256)
xstage(const float* __restrict__ x_dyn, unsigned short* __restrict__ xg)
{
    const int rb = blockIdx.x * ROWS;
    for (int idx = threadIdx.x; idx < T_STEPS * ROWS; idx += 256) {
        const int t = idx % T_STEPS, r = idx / T_STEPS;
        const float* s = x_dyn + (size_t)(rb + r) * XLEN + t * 3;
        bf16x4 pk;
        pk[0] = (short)f2bf(s[0]); pk[1] = (short)f2bf(s[1]);
        pk[2] = (short)f2bf(s[2]); pk[3] = (short)0x3F80;   // 1.0 bf16
        *(bf16x4*)&xg[((size_t)blockIdx.x * T_STEPS + t) * 64 + r * 4] = pk;
    }
}

// Round-14 = Round-10 structure (best, 569 us) + two stall fixes:
//   (a) ALL 16 o-gate A-frags prefetched to regs at step top (one lgkmcnt
//       wait) -- R10 left them inline in the MFMA stream, exposing ~120-cyc
//       LDS latency per read inside the dependency chains.
//   (b) fused-rcp gate algebra: 6 trans/element instead of 8
//       c' = (c(1+Eg) + i(1-Eg)(1+Ef)) * rcp((1+Ef)(1+Eg))
//       h  = (1-Ec) * rcp((1+Eo)(1+Ec))
//   (c) expand4(wX) hoisted out of the step loop.
__global__ void __launch_bounds__(512, 2)
ealstm_fused(const unsigned short* __restrict__ xg, const float* __restrict__ x_stat,
             const float* __restrict__ w_i, const float* __restrict__ b_i,
             const float* __restrict__ w_f, const float* __restrict__ b_f,
             const float* __restrict__ w_g, const float* __restrict__ b_g,
             const float* __restrict__ w_o, const float* __restrict__ b_o,
             const float* __restrict__ w_head, const float* __restrict__ b_head,
             float* __restrict__ out)
{
    const int tid   = threadIdx.x;
    const int lane  = tid & 63;
    const int wv    = tid >> 6;       // 0..7
    const int m     = lane & 15;      // batch row (N dim of D)
    const int l16   = lane >> 4;      // 0..3
    const int rb    = blockIdx.x * ROWS;
    const int wbase = wv * CPW;

    __shared__ unsigned short wo_lds[4 * 8 * 256 * 8];    // 128 KB [l16][kt][c][e]
    __shared__ unsigned short hbuf[2][4096];              // 16 KB h^T B-pack, dbuf
    __shared__ float          red[NW][ROWS];

    // ---- one-time staging ----
    for (int idx = tid; idx < 4 * 8 * 8 * 256; idx += 512) {
        const int c    = idx & 255;
        const int e    = (idx >> 8) & 7;
        const int kt   = (idx >> 11) & 7;
        const int l16g = idx >> 14;
        wo_lds[((l16g * 8 + kt) * 256 + c) * 8 + e] =
            f2bf(SF1 * w_o[(3 + kt * 32 + l16g * 8 + e) * H_SZ + c]);
    }
    for (int idx = tid; idx < 2048; idx += 512) ((unsigned int*)hbuf[0])[idx] = 0u;

    const float* wsrc[3] = {w_f, w_g, w_o};
    const float* bsrc[3] = {b_f, b_g, b_o};
    const float  gsf[3]  = {SF1, SF2, SF1};

    // ---- weights -> registers (pre-scaled) ----
    bf16x8 wA[8][2][2];      // f,g gates, all 8 kt = 128 regs (AGPR side)
    bf16x8 wXe[2][3];        // x/bias tile, pre-expanded (24 regs); l16==0 only
#pragma unroll
    for (int ct = 0; ct < 2; ++ct) {
        const int c = wbase + ct * 16 + m;
#pragma unroll
        for (int g = 0; g < 2; ++g)
#pragma unroll
            for (int kt = 0; kt < 8; ++kt) {
                bf16x8 a;
#pragma unroll
                for (int e = 0; e < 8; ++e)
                    a[e] = (short)f2bf(gsf[g] * wsrc[g][(3 + kt * 32 + l16 * 8 + e) * H_SZ + c]);
                wA[kt][ct][g] = a;
            }
#pragma unroll
        for (int g = 0; g < 3; ++g) {
            bf16x4 ax = (bf16x4)0;
            if (l16 == 0) {
                ax[0] = (short)f2bf(gsf[g] * wsrc[g][0 * H_SZ + c]);
                ax[1] = (short)f2bf(gsf[g] * wsrc[g][1 * H_SZ + c]);
                ax[2] = (short)f2bf(gsf[g] * wsrc[g][2 * H_SZ + c]);
                ax[3] = (short)f2bf(gsf[g] * bsrc[g][c]);
            }
            wXe[ct][g] = expand4(ax);
        }
    }

    // ---- static input gate (fp32 regs) + cell state ----
    float iv[2][4], cst[2][4];
    {
        const float xs0 = x_stat[(rb + m) * 3 + 0];
        const float xs1 = x_stat[(rb + m) * 3 + 1];
        const float xs2 = x_stat[(rb + m) * 3 + 2];
#pragma unroll
        for (int ct = 0; ct < 2; ++ct)
#pragma unroll
            for (int q = 0; q < 4; ++q) {
                const int c = wbase + ct * 16 + l16 * 4 + q;
                iv[ct][q] = fast_sigmoid(b_i[c] + xs0 * w_i[c] + xs1 * w_i[H_SZ + c]
                                                + xs2 * w_i[2 * H_SZ + c]);
                cst[ct][q] = 0.0f;
            }
    }

    // h-write offsets: c0 = wbase+ct*16+l16*4; kt=c0>>5; L=m+16*((c0&31)>>3); e=c0&7
    int woff[2];
#pragma unroll
    for (int ct = 0; ct < 2; ++ct) {
        const int c0 = wbase + ct * 16 + l16 * 4;
        woff[ct] = ((c0 >> 5) * 64 + m + 16 * ((c0 & 31) >> 3)) * 8 + (c0 & 7);
    }

    // loop-invariant base pointers
    const unsigned short* xrow   = xg + (size_t)blockIdx.x * T_STEPS * 64 + m * 4;
    const bf16x8*         wobase = (const bf16x8*)&wo_lds[((l16 * 8) * 256 + wbase + m) * 8];

    __syncthreads();

    for (int t = 0; t < T_STEPS; ++t) {
        const int cur = t & 1;
        const bf16x8* hp = (const bf16x8*)hbuf[cur] + lane;
        unsigned short* hw = hbuf[cur ^ 1];

        // ---- all reads up front: x, h B-frags, AND o-gate A-frags ----
        bf16x8 xf = (bf16x8)0;
        {
            unsigned long long xv = *(const unsigned long long*)&xrow[(size_t)t * 64];
            if (l16 != 0) xv = 0ULL;
            union { unsigned long long u; bf16x4 v; } X; X.u = xv;
            xf[0] = X.v[0]; xf[1] = X.v[1]; xf[2] = X.v[2]; xf[3] = X.v[3];
        }
        bf16x8 hb[8];
#pragma unroll
        for (int kt = 0; kt < 8; ++kt) hb[kt] = hp[kt * 64];
        bf16x8 wor[8][2];
#pragma unroll
        for (int kt = 0; kt < 8; ++kt) {
            wor[kt][0] = wobase[kt * 256];           // imm kt*4096
            wor[kt][1] = wobase[kt * 256 + 16];      // imm kt*4096+256
        }

        // acc init: z = x @ Wx + b via x-tile MFMA
        f32x4 acc[2][3];
        {
            const f32x4 z4 = {0.f, 0.f, 0.f, 0.f};
#pragma unroll
            for (int ct = 0; ct < 2; ++ct)
#pragma unroll
                for (int g = 0; g < 3; ++g)
                    acc[ct][g] = __builtin_amdgcn_mfma_f32_16x16x32_bf16(
                        wXe[ct][g], xf, z4, 0, 0, 0);
        }

        // z += h @ Wh : all operands in registers, stall-free stream
#pragma unroll
        for (int kt = 0; kt < 8; ++kt) {
            acc[0][0] = __builtin_amdgcn_mfma_f32_16x16x32_bf16(wA[kt][0][0], hb[kt], acc[0][0], 0, 0, 0);
            acc[0][1] = __builtin_amdgcn_mfma_f32_16x16x32_bf16(wA[kt][0][1], hb[kt], acc[0][1], 0, 0, 0);
            acc[0][2] = __builtin_amdgcn_mfma_f32_16x16x32_bf16(wor[kt][0],   hb[kt], acc[0][2], 0, 0, 0);
            acc[1][0] = __builtin_amdgcn_mfma_f32_16x16x32_bf16(wA[kt][1][0], hb[kt], acc[1][0], 0, 0, 0);
            acc[1][1] = __builtin_amdgcn_mfma_f32_16x16x32_bf16(wA[kt][1][1], hb[kt], acc[1][1], 0, 0, 0);
            acc[1][2] = __builtin_amdgcn_mfma_f32_16x16x32_bf16(wor[kt][1],   hb[kt], acc[1][2], 0, 0, 0);
        }

        // gates + state (fused-rcp algebra: 4 exp2 + 2 rcp per element)
#pragma unroll
        for (int ct = 0; ct < 2; ++ct) {
            bf16x4 pk;
#pragma unroll
            for (int q = 0; q < 4; ++q) {
                const float Ef = __builtin_amdgcn_exp2f(acc[ct][0][q]);
                const float Eg = __builtin_amdgcn_exp2f(acc[ct][1][q]);
                const float Eo = __builtin_amdgcn_exp2f(acc[ct][2][q]);
                const float u  = 1.0f + Eg;                   // 1+Eg
                const float v  = 1.0f + Ef;                   // 1+Ef
                const float t2 = iv[ct][q] * (2.0f - u);      // i*(1-Eg)
                const float cq = (cst[ct][q] * u + t2 * v) *
                                 __builtin_amdgcn_rcpf(u * v);
                cst[ct][q] = cq;
                const float Ec = __builtin_amdgcn_exp2f(SF2 * cq);
                const float hq = (1.0f - Ec) *
                                 __builtin_amdgcn_rcpf((1.0f + Eo) * (1.0f + Ec));
                pk[q] = (short)f2bf(hq);
            }
            *(bf16x4*)&hw[woff[ct]] = pk;
        }
        __syncthreads();
    }

    // ---- head: out[r] = sum_c h[r][c] w_head[c] + b_head ----
    float p = 0.0f;
    const unsigned short* hf = hbuf[1];   // t=364: cur=0, wrote hbuf[1]
#pragma unroll
    for (int ct = 0; ct < 2; ++ct) {
        const int c0 = wbase + ct * 16 + l16 * 4;
        const f32x4 wh = *(const f32x4*)&w_head[c0];
        const bf16x4 hv = *(const bf16x4*)&hf[woff[ct]];
#pragma unroll
        for (int q = 0; q < 4; ++q) p += bf2f((unsigned short)hv[q]) * wh[q];
    }
    p += __shfl_xor(p, 16);
    p += __shfl_xor(p, 32);
    if (lane < 16) red[wv][m] = p;
    __syncthreads();
    if (tid < ROWS) {
        float s = b_head[0];
#pragma unroll
        for (int w = 0; w < NW; ++w) s += red[w][tid];
        out[rb + tid] = s;
    }
}

extern "C" void kernel_launch(void* const* d_in, const int* in_sizes, int n_in,
                              void* d_out, int out_size, void* d_ws, size_t ws_size,
                              hipStream_t stream)
{
    const float* x_dyn  = (const float*)d_in[0];
    const float* x_stat = (const float*)d_in[1];
    const float* w_i    = (const float*)d_in[2];
    const float* b_i    = (const float*)d_in[3];
    const float* w_f    = (const float*)d_in[4];
    const float* b_f    = (const float*)d_in[5];
    const float* w_g    = (const float*)d_in[6];
    const float* b_g    = (const float*)d_in[7];
    const float* w_o    = (const float*)d_in[8];
    const float* b_o    = (const float*)d_in[9];
    const float* w_head = (const float*)d_in[10];
    const float* b_head = (const float*)d_in[11];

    unsigned short* xg = (unsigned short*)d_ws;   // 64*365*64*2 B = 2.99 MB

    xstage<<<dim3(64), dim3(256), 0, stream>>>(x_dyn, xg);
    ealstm_fused<<<dim3(64), dim3(512), 0, stream>>>(
        xg, x_stat, w_i, b_i, w_f, b_f, w_g, b_g, w_o, b_o,
        w_head, b_head, (float*)d_out);
}

// Round 15
// 526.575 us; speedup vs baseline: 1.3828x; 1.0979x over previous
//
#include <hip/hip_runtime.h>
#include <hip/hip_bf16.h>

#define T_STEPS 365
#define XLEN    (T_STEPS * 3)
#define H_SZ    256
#define ROWS    8      // batch rows per block (128 blocks)
#define NBLK    128
#define NW      8      // waves per block (2 per SIMD)
#define CPW     32     // state cols per wave

#define SF1     (-1.4426950408889634f)   // -log2(e): folded into W_f, W_o
#define SF2     (-2.8853900817779268f)   // -2 log2(e): folded into W_g, tanh(c)

typedef __attribute__((ext_vector_type(8))) short bf16x8;   // 8 bf16 = 4 VGPRs
typedef __attribute__((ext_vector_type(4))) short bf16x4;   // 4 bf16 = 2 VGPRs
typedef __attribute__((ext_vector_type(4))) float f32x4;

__device__ __forceinline__ float fast_sigmoid(float x) {    // plain form (iv only)
    return __builtin_amdgcn_rcpf(1.0f + __builtin_amdgcn_exp2f(-1.44269504f * x));
}
__device__ __forceinline__ unsigned short f2bf(float x) {   // fp32 -> bf16 RTNE
    __hip_bfloat16 b = __float2bfloat16(x);
    return *reinterpret_cast<unsigned short*>(&b);
}
__device__ __forceinline__ float bf2f(unsigned short v) {
    return __uint_as_float(((unsigned)v) << 16);
}
__device__ __forceinline__ bf16x8 expand4(bf16x4 v) {       // {v0..v3,0,0,0,0}
    bf16x8 r = (bf16x8)0;
    r[0] = v[0]; r[1] = v[1]; r[2] = v[2]; r[3] = v[3];
    return r;
}

// pre-kernel: pack x_dyn -> d_ws as bf16 {x0,x1,x2,1.0} per (block,t,row<8)
__global__ void __launch_bounds__(256)
xstage(const float* __restrict__ x_dyn, unsigned short* __restrict__ xg)
{
    const int rb = blockIdx.x * ROWS;
    for (int idx = threadIdx.x; idx < T_STEPS * ROWS; idx += 256) {
        const int t = idx % T_STEPS, r = idx / T_STEPS;
        const float* s = x_dyn + (size_t)(rb + r) * XLEN + t * 3;
        bf16x4 pk;
        pk[0] = (short)f2bf(s[0]); pk[1] = (short)f2bf(s[1]);
        pk[2] = (short)f2bf(s[2]); pk[3] = (short)0x3F80;   // 1.0 bf16
        *(bf16x4*)&xg[((size_t)blockIdx.x * T_STEPS + t) * 32 + r * 4] = pk;
    }
}

// Round-15: issue-budget attack. 128 blocks x 8 rows; MFMA per CU unchanged
// (B rows 8-15 zero => D=0 there), but gate work redistributed so EVERY lane
// processes 4 elements instead of 8:
//   lane m<8 : (row m,   ct=0) -- own acc[0]
//   lane m>=8: (row m-8, ct=1) -- partner's acc[1] via one __shfl_xor(.,8)
// cst/iv live in the processing lane; h written directly from it (no
// shuffle-back). Trans issue per SIMD halves (768 -> 384 cyc).
// Base otherwise = round 14 (reg-resident wo prefetch, fused-rcp gates).
__global__ void __launch_bounds__(512, 2)
ealstm_fused(const unsigned short* __restrict__ xg, const float* __restrict__ x_stat,
             const float* __restrict__ w_i, const float* __restrict__ b_i,
             const float* __restrict__ w_f, const float* __restrict__ b_f,
             const float* __restrict__ w_g, const float* __restrict__ b_g,
             const float* __restrict__ w_o, const float* __restrict__ b_o,
             const float* __restrict__ w_head, const float* __restrict__ b_head,
             float* __restrict__ out)
{
    const int tid   = threadIdx.x;
    const int lane  = tid & 63;
    const int wv    = tid >> 6;       // 0..7
    const int m     = lane & 15;      // B-operand row slot (batch row if <8)
    const int l16   = lane >> 4;      // 0..3
    const int rb    = blockIdx.x * ROWS;
    const int wbase = wv * CPW;
    const int r_eff  = m & 7;         // batch row this lane GATES
    const int ct_eff = m >> 3;        // ct tile this lane GATES
    const bool hi    = (m >= 8);

    __shared__ unsigned short wo_lds[4 * 8 * 256 * 8];    // 128 KB [l16][kt][c][e]
    __shared__ unsigned short hbuf[2][4096];              // 16 KB h^T B-pack, dbuf
    __shared__ float          red[NW][ROWS];

    // ---- one-time staging ----
    for (int idx = tid; idx < 4 * 8 * 8 * 256; idx += 512) {
        const int c    = idx & 255;
        const int e    = (idx >> 8) & 7;
        const int kt   = (idx >> 11) & 7;
        const int l16g = idx >> 14;
        wo_lds[((l16g * 8 + kt) * 256 + c) * 8 + e] =
            f2bf(SF1 * w_o[(3 + kt * 32 + l16g * 8 + e) * H_SZ + c]);
    }
    // zero BOTH h buffers: row slots (L&15)>=8 must stay zero forever
    for (int idx = tid; idx < 4096; idx += 512) ((unsigned int*)hbuf)[idx] = 0u;

    const float* wsrc[3] = {w_f, w_g, w_o};
    const float* bsrc[3] = {b_f, b_g, b_o};
    const float  gsf[3]  = {SF1, SF2, SF1};

    // ---- weights -> registers (pre-scaled); layouts unchanged ----
    bf16x8 wA[8][2][2];      // f,g gates, all 8 kt = 128 regs (AGPR side)
    bf16x8 wXe[2][3];        // x/bias tile, pre-expanded; l16==0 only
#pragma unroll
    for (int ct = 0; ct < 2; ++ct) {
        const int c = wbase + ct * 16 + m;
#pragma unroll
        for (int g = 0; g < 2; ++g)
#pragma unroll
            for (int kt = 0; kt < 8; ++kt) {
                bf16x8 a;
#pragma unroll
                for (int e = 0; e < 8; ++e)
                    a[e] = (short)f2bf(gsf[g] * wsrc[g][(3 + kt * 32 + l16 * 8 + e) * H_SZ + c]);
                wA[kt][ct][g] = a;
            }
#pragma unroll
        for (int g = 0; g < 3; ++g) {
            bf16x4 ax = (bf16x4)0;
            if (l16 == 0) {
                ax[0] = (short)f2bf(gsf[g] * wsrc[g][0 * H_SZ + c]);
                ax[1] = (short)f2bf(gsf[g] * wsrc[g][1 * H_SZ + c]);
                ax[2] = (short)f2bf(gsf[g] * wsrc[g][2 * H_SZ + c]);
                ax[3] = (short)f2bf(gsf[g] * bsrc[g][c]);
            }
            wXe[ct][g] = expand4(ax);
        }
    }

    // ---- static input gate + cell state (for this lane's 4 gate elements) ----
    const int c0 = wbase + ct_eff * 16 + l16 * 4;
    float iv[4], cst[4];
    {
        const float xs0 = x_stat[(rb + r_eff) * 3 + 0];
        const float xs1 = x_stat[(rb + r_eff) * 3 + 1];
        const float xs2 = x_stat[(rb + r_eff) * 3 + 2];
#pragma unroll
        for (int q = 0; q < 4; ++q) {
            const int c = c0 + q;
            iv[q] = fast_sigmoid(b_i[c] + xs0 * w_i[c] + xs1 * w_i[H_SZ + c]
                                        + xs2 * w_i[2 * H_SZ + c]);
            cst[q] = 0.0f;
        }
    }

    // h-write offset for this lane's 4 cols, row r_eff (B-pack slot formula)
    const int woff = ((c0 >> 5) * 64 + r_eff + 16 * ((c0 & 31) >> 3)) * 8 + (c0 & 7);

    // loop-invariant base pointers
    const unsigned short* xrow   = xg + (size_t)blockIdx.x * T_STEPS * 32 + m * 4;
    const bf16x8*         wobase = (const bf16x8*)&wo_lds[((l16 * 8) * 256 + wbase + m) * 8];

    __syncthreads();

    for (int t = 0; t < T_STEPS; ++t) {
        const int cur = t & 1;
        const bf16x8* hp = (const bf16x8*)hbuf[cur] + lane;
        unsigned short* hw = hbuf[cur ^ 1];

        // ---- all reads up front: x, h B-frags, o-gate A-frags ----
        bf16x8 xf = (bf16x8)0;
        if (l16 == 0 && m < 8) {
            const bf16x4 v = *(const bf16x4*)&xrow[(size_t)t * 32];
            xf[0] = v[0]; xf[1] = v[1]; xf[2] = v[2]; xf[3] = v[3];
        }
        bf16x8 hb[8];
#pragma unroll
        for (int kt = 0; kt < 8; ++kt) hb[kt] = hp[kt * 64];
        bf16x8 wor[8][2];
#pragma unroll
        for (int kt = 0; kt < 8; ++kt) {
            wor[kt][0] = wobase[kt * 256];           // imm kt*4096
            wor[kt][1] = wobase[kt * 256 + 16];      // imm kt*4096+256
        }

        // acc init: z = x @ Wx + b via x-tile MFMA
        f32x4 acc[2][3];
        {
            const f32x4 z4 = {0.f, 0.f, 0.f, 0.f};
#pragma unroll
            for (int ct = 0; ct < 2; ++ct)
#pragma unroll
                for (int g = 0; g < 3; ++g)
                    acc[ct][g] = __builtin_amdgcn_mfma_f32_16x16x32_bf16(
                        wXe[ct][g], xf, z4, 0, 0, 0);
        }

        // z += h @ Wh : all operands in registers
#pragma unroll
        for (int kt = 0; kt < 8; ++kt) {
            acc[0][0] = __builtin_amdgcn_mfma_f32_16x16x32_bf16(wA[kt][0][0], hb[kt], acc[0][0], 0, 0, 0);
            acc[0][1] = __builtin_amdgcn_mfma_f32_16x16x32_bf16(wA[kt][0][1], hb[kt], acc[0][1], 0, 0, 0);
            acc[0][2] = __builtin_amdgcn_mfma_f32_16x16x32_bf16(wor[kt][0],   hb[kt], acc[0][2], 0, 0, 0);
            acc[1][0] = __builtin_amdgcn_mfma_f32_16x16x32_bf16(wA[kt][1][0], hb[kt], acc[1][0], 0, 0, 0);
            acc[1][1] = __builtin_amdgcn_mfma_f32_16x16x32_bf16(wA[kt][1][1], hb[kt], acc[1][1], 0, 0, 0);
            acc[1][2] = __builtin_amdgcn_mfma_f32_16x16x32_bf16(wor[kt][1],   hb[kt], acc[1][2], 0, 0, 0);
        }

        // ---- gate redistribution: lane m>=8 takes (row m-8, ct=1) ----
        float zf[4], zg[4], zo[4];
#pragma unroll
        for (int q = 0; q < 4; ++q) {
            const float sf = __shfl_xor(acc[1][0][q], 8);
            const float sg = __shfl_xor(acc[1][1][q], 8);
            const float so = __shfl_xor(acc[1][2][q], 8);
            zf[q] = hi ? sf : acc[0][0][q];
            zg[q] = hi ? sg : acc[0][1][q];
            zo[q] = hi ? so : acc[0][2][q];
        }

        // gates + state (fused-rcp: 4 exp2 + 2 rcp per element; 4 elem/lane)
        {
            bf16x4 pk;
#pragma unroll
            for (int q = 0; q < 4; ++q) {
                const float Ef = __builtin_amdgcn_exp2f(zf[q]);
                const float Eg = __builtin_amdgcn_exp2f(zg[q]);
                const float Eo = __builtin_amdgcn_exp2f(zo[q]);
                const float u  = 1.0f + Eg;
                const float v  = 1.0f + Ef;
                const float t2 = iv[q] * (2.0f - u);          // i*(1-Eg)
                const float cq = (cst[q] * u + t2 * v) *
                                 __builtin_amdgcn_rcpf(u * v);
                cst[q] = cq;
                const float Ec = __builtin_amdgcn_exp2f(SF2 * cq);
                const float hq = (1.0f - Ec) *
                                 __builtin_amdgcn_rcpf((1.0f + Eo) * (1.0f + Ec));
                pk[q] = (short)f2bf(hq);
            }
            *(bf16x4*)&hw[woff] = pk;
        }
        __syncthreads();
    }

    // ---- head: out[r] = sum_c h[r][c] w_head[c] + b_head ----
    float p = 0.0f;
    {
        const unsigned short* hf = hbuf[1];   // t=364: cur=0, wrote hbuf[1]
        const f32x4 wh = *(const f32x4*)&w_head[c0];
        const bf16x4 hv = *(const bf16x4*)&hf[woff];
#pragma unroll
        for (int q = 0; q < 4; ++q) p += bf2f((unsigned short)hv[q]) * wh[q];
    }
    p += __shfl_xor(p, 8);    // combine ct0/ct1 halves (same r_eff)
    p += __shfl_xor(p, 16);   // combine l16 groups
    p += __shfl_xor(p, 32);
    if (lane < ROWS) red[wv][lane] = p;
    __syncthreads();
    if (tid < ROWS) {
        float s = b_head[0];
#pragma unroll
        for (int w = 0; w < NW; ++w) s += red[w][tid];
        out[rb + tid] = s;
    }
}

extern "C" void kernel_launch(void* const* d_in, const int* in_sizes, int n_in,
                              void* d_out, int out_size, void* d_ws, size_t ws_size,
                              hipStream_t stream)
{
    const float* x_dyn  = (const float*)d_in[0];
    const float* x_stat = (const float*)d_in[1];
    const float* w_i    = (const float*)d_in[2];
    const float* b_i    = (const float*)d_in[3];
    const float* w_f    = (const float*)d_in[4];
    const float* b_f    = (const float*)d_in[5];
    const float* w_g    = (const float*)d_in[6];
    const float* b_g    = (const float*)d_in[7];
    const float* w_o    = (const float*)d_in[8];
    const float* b_o    = (const float*)d_in[9];
    const float* w_head = (const float*)d_in[10];
    const float* b_head = (const float*)d_in[11];

    unsigned short* xg = (unsigned short*)d_ws;   // 128*365*32*2 B = 2.99 MB

    xstage<<<dim3(NBLK), dim3(256), 0, stream>>>(x_dyn, xg);
    ealstm_fused<<<dim3(NBLK), dim3(512), 0, stream>>>(
        xg, x_stat, w_i, b_i, w_f, b_f, w_g, b_g, w_o, b_o,
        w_head, b_head, (float*)d_out);
}

// Round 16
// 523.490 us; speedup vs baseline: 1.3910x; 1.0059x over previous
//
#include <hip/hip_runtime.h>
#include <hip/hip_bf16.h>

#define T_STEPS 365
#define XLEN    (T_STEPS * 3)
#define H_SZ    256
#define ROWS    4      // batch rows per block (256 blocks, 1 per CU)
#define NBLK    256
#define NW      8      // waves per block (2 per SIMD)
#define CPW     32     // state cols per wave

#define SF1     (-1.4426950408889634f)   // -log2(e): folded into W_f, W_o
#define SF2     (-2.8853900817779268f)   // -2 log2(e): folded into W_g, tanh(c)

typedef __attribute__((ext_vector_type(8))) short bf16x8;   // 8 bf16 = 4 VGPRs
typedef __attribute__((ext_vector_type(4))) short bf16x4;   // 4 bf16 = 2 VGPRs
typedef __attribute__((ext_vector_type(4))) float f32x4;

__device__ __forceinline__ float fast_sigmoid(float x) {    // plain form (iv only)
    return __builtin_amdgcn_rcpf(1.0f + __builtin_amdgcn_exp2f(-1.44269504f * x));
}
__device__ __forceinline__ unsigned short f2bf(float x) {   // fp32 -> bf16 RTNE
    __hip_bfloat16 b = __float2bfloat16(x);
    return *reinterpret_cast<unsigned short*>(&b);
}
__device__ __forceinline__ float bf2f(unsigned short v) {
    return __uint_as_float(((unsigned)v) << 16);
}

// Round-16: issue-minimal serial step.
//   * ROWS=4, 256 blocks (all CUs). 2-stage gate redistribution:
//     stage A xor-8 (ct split), stage B xor-4 (q-pair split) ->
//     lane m: row m&3, ct m>>3, q-pair (m>>2)&1 -> 2 gate elems/lane.
//     trans issue/SIMD: 384 -> 192 cyc.
//   * x-tile MFMA DELETED (48 of 432 MFMAs/CU): z_x = x@Wx + b computed
//     on VALU post-shuffle from 24 resident f32 coef regs; x read straight
//     from x_dyn (17.5 KB/block slice -> L1). xstage kernel deleted.
//   * base otherwise = R15 (pre-scaled weights, fused-rcp gates, o in LDS).
__global__ void __launch_bounds__(512, 2)
ealstm_fused(const float* __restrict__ x_dyn, const float* __restrict__ x_stat,
             const float* __restrict__ w_i, const float* __restrict__ b_i,
             const float* __restrict__ w_f, const float* __restrict__ b_f,
             const float* __restrict__ w_g, const float* __restrict__ b_g,
             const float* __restrict__ w_o, const float* __restrict__ b_o,
             const float* __restrict__ w_head, const float* __restrict__ b_head,
             float* __restrict__ out)
{
    const int tid   = threadIdx.x;
    const int lane  = tid & 63;
    const int wv    = tid >> 6;       // 0..7
    const int m     = lane & 15;      // B-operand row slot
    const int l16   = lane >> 4;      // 0..3
    const int rb    = blockIdx.x * ROWS;
    const int wbase = wv * CPW;

    const int r_eff  = m & 3;         // batch row this lane GATES
    const int ct_eff = m >> 3;        // ct tile this lane GATES (stage A bit)
    const int qp     = ((m >> 2) & 1) * 2;   // q-pair base (stage B bit)

    __shared__ unsigned short wo_lds[4 * 8 * 256 * 8];    // 128 KB [l16][kt][c][e]
    __shared__ unsigned short hbuf[2][4096];              // 16 KB h^T B-pack, dbuf
    __shared__ float          red[NW][ROWS];

    // ---- one-time staging ----
    for (int idx = tid; idx < 4 * 8 * 8 * 256; idx += 512) {
        const int c    = idx & 255;
        const int e    = (idx >> 8) & 7;
        const int kt   = (idx >> 11) & 7;
        const int l16g = idx >> 14;
        wo_lds[((l16g * 8 + kt) * 256 + c) * 8 + e] =
            f2bf(SF1 * w_o[(3 + kt * 32 + l16g * 8 + e) * H_SZ + c]);
    }
    // zero BOTH h buffers: row slots (L&15)>=4 must stay zero forever
    for (int idx = tid; idx < 4096; idx += 512) ((unsigned int*)hbuf)[idx] = 0u;

    const float* wsrc[3] = {w_f, w_g, w_o};
    const float* bsrc[3] = {b_f, b_g, b_o};
    const float  gsf[3]  = {SF1, SF2, SF1};

    // ---- recurrent weights -> registers (pre-scaled); layout unchanged ----
    bf16x8 wA[8][2][2];      // f,g gates, all 8 kt = 128 regs (AGPR side)
#pragma unroll
    for (int ct = 0; ct < 2; ++ct) {
        const int c = wbase + ct * 16 + m;
#pragma unroll
        for (int g = 0; g < 2; ++g)
#pragma unroll
            for (int kt = 0; kt < 8; ++kt) {
                bf16x8 a;
#pragma unroll
                for (int e = 0; e < 8; ++e)
                    a[e] = (short)f2bf(gsf[g] * wsrc[g][(3 + kt * 32 + l16 * 8 + e) * H_SZ + c]);
                wA[kt][ct][g] = a;
            }
    }

    // ---- x/bias coefs for this lane's 2 gate elements (24 f32 regs) ----
    // cw(e) = wbase + ct_eff*16 + l16*4 + qp + e, e in {0,1}
    const int cw0 = wbase + ct_eff * 16 + l16 * 4 + qp;
    f32x4 cxw[2][3];    // [elem][gate] = {w0,w1,w2,b} pre-scaled
#pragma unroll
    for (int e = 0; e < 2; ++e)
#pragma unroll
        for (int g = 0; g < 3; ++g) {
            const int c = cw0 + e;
            f32x4 v;
            v[0] = gsf[g] * wsrc[g][0 * H_SZ + c];
            v[1] = gsf[g] * wsrc[g][1 * H_SZ + c];
            v[2] = gsf[g] * wsrc[g][2 * H_SZ + c];
            v[3] = gsf[g] * bsrc[g][c];
            cxw[e][g] = v;
        }

    // ---- static input gate + cell state (2 elements) ----
    float iv[2], cst[2];
    {
        const float xs0 = x_stat[(rb + r_eff) * 3 + 0];
        const float xs1 = x_stat[(rb + r_eff) * 3 + 1];
        const float xs2 = x_stat[(rb + r_eff) * 3 + 2];
#pragma unroll
        for (int e = 0; e < 2; ++e) {
            const int c = cw0 + e;
            iv[e] = fast_sigmoid(b_i[c] + xs0 * w_i[c] + xs1 * w_i[H_SZ + c]
                                        + xs2 * w_i[2 * H_SZ + c]);
            cst[e] = 0.0f;
        }
    }

    // h-write offset: col cw0 (even), row r_eff -> B-pack slot; ushort2 write
    const int kw  = cw0 >> 5;
    const int kp  = cw0 & 31;
    const int woff = ((kw * 64) + r_eff + 16 * (kp >> 3)) * 8 + (kp & 7);

    // loop-invariant base pointers
    const float*  xr     = x_dyn + (size_t)(rb + r_eff) * XLEN;
    const bf16x8* wobase = (const bf16x8*)&wo_lds[((l16 * 8) * 256 + wbase + m) * 8];

    __syncthreads();

    for (int t = 0; t < T_STEPS; ++t) {
        const int cur = t & 1;
        const bf16x8* hp = (const bf16x8*)hbuf[cur] + lane;
        unsigned short* hw = hbuf[cur ^ 1];

        // x for this lane's row (L1-resident, broadcast across 16 lanes)
        const float x0 = xr[t * 3 + 0];
        const float x1 = xr[t * 3 + 1];
        const float x2 = xr[t * 3 + 2];

        // ---- z = h @ Wh : 48 MFMAs/wave, kt0 inits from zero ----
        f32x4 acc[2][3];
        {
            const f32x4 z4 = {0.f, 0.f, 0.f, 0.f};
            const bf16x8 b0  = hp[0];
            const bf16x8 wo0 = wobase[0];
            const bf16x8 wo1 = wobase[16];
            acc[0][0] = __builtin_amdgcn_mfma_f32_16x16x32_bf16(wA[0][0][0], b0, z4, 0, 0, 0);
            acc[0][1] = __builtin_amdgcn_mfma_f32_16x16x32_bf16(wA[0][0][1], b0, z4, 0, 0, 0);
            acc[0][2] = __builtin_amdgcn_mfma_f32_16x16x32_bf16(wo0,         b0, z4, 0, 0, 0);
            acc[1][0] = __builtin_amdgcn_mfma_f32_16x16x32_bf16(wA[0][1][0], b0, z4, 0, 0, 0);
            acc[1][1] = __builtin_amdgcn_mfma_f32_16x16x32_bf16(wA[0][1][1], b0, z4, 0, 0, 0);
            acc[1][2] = __builtin_amdgcn_mfma_f32_16x16x32_bf16(wo1,         b0, z4, 0, 0, 0);
        }
#pragma unroll
        for (int kt = 1; kt < 8; ++kt) {
            const bf16x8 b   = hp[kt * 64];
            const bf16x8 wo0 = wobase[kt * 256];           // imm kt*4096
            const bf16x8 wo1 = wobase[kt * 256 + 16];      // imm kt*4096+256
            acc[0][0] = __builtin_amdgcn_mfma_f32_16x16x32_bf16(wA[kt][0][0], b, acc[0][0], 0, 0, 0);
            acc[0][1] = __builtin_amdgcn_mfma_f32_16x16x32_bf16(wA[kt][0][1], b, acc[0][1], 0, 0, 0);
            acc[0][2] = __builtin_amdgcn_mfma_f32_16x16x32_bf16(wo0,          b, acc[0][2], 0, 0, 0);
            acc[1][0] = __builtin_amdgcn_mfma_f32_16x16x32_bf16(wA[kt][1][0], b, acc[1][0], 0, 0, 0);
            acc[1][1] = __builtin_amdgcn_mfma_f32_16x16x32_bf16(wA[kt][1][1], b, acc[1][1], 0, 0, 0);
            acc[1][2] = __builtin_amdgcn_mfma_f32_16x16x32_bf16(wo1,          b, acc[1][2], 0, 0, 0);
        }

        // ---- 2-stage gate redistribution ----
        // stage A (xor 8): lanes m>=8 take ct=1 values for row m&7
        float zA[3][4];
#pragma unroll
        for (int q = 0; q < 4; ++q) {
#pragma unroll
            for (int g = 0; g < 3; ++g) {
                const float s = __shfl_xor(acc[1][g][q], 8);
                zA[g][q] = (m >= 8) ? s : acc[0][g][q];
            }
        }
        // stage B (xor 4): lanes with m&4 take partner's q={2,3} as their pair
        float z[3][2];
#pragma unroll
        for (int g = 0; g < 3; ++g) {
            const float u2 = __shfl_xor(zA[g][2], 4);
            const float u3 = __shfl_xor(zA[g][3], 4);
            z[g][0] = (m & 4) ? u2 : zA[g][0];
            z[g][1] = (m & 4) ? u3 : zA[g][1];
        }

        // ---- z += x @ Wx + b (VALU, fp32 coefs) ; gates; h-write ----
        unsigned short h2[2];
#pragma unroll
        for (int e = 0; e < 2; ++e) {
            const float zf = z[0][e] + cxw[e][0][3] + x0 * cxw[e][0][0] + x1 * cxw[e][0][1] + x2 * cxw[e][0][2];
            const float zg = z[1][e] + cxw[e][1][3] + x0 * cxw[e][1][0] + x1 * cxw[e][1][1] + x2 * cxw[e][1][2];
            const float zo = z[2][e] + cxw[e][2][3] + x0 * cxw[e][2][0] + x1 * cxw[e][2][1] + x2 * cxw[e][2][2];
            const float Ef = __builtin_amdgcn_exp2f(zf);
            const float Eg = __builtin_amdgcn_exp2f(zg);
            const float Eo = __builtin_amdgcn_exp2f(zo);
            const float u  = 1.0f + Eg;
            const float v  = 1.0f + Ef;
            const float t2 = iv[e] * (2.0f - u);          // i*(1-Eg)
            const float cq = (cst[e] * u + t2 * v) * __builtin_amdgcn_rcpf(u * v);
            cst[e] = cq;
            const float Ec = __builtin_amdgcn_exp2f(SF2 * cq);
            const float hq = (1.0f - Ec) * __builtin_amdgcn_rcpf((1.0f + Eo) * (1.0f + Ec));
            h2[e] = f2bf(hq);
        }
        {
            unsigned int pk = (unsigned)h2[0] | ((unsigned)h2[1] << 16);
            *(unsigned int*)&hw[woff] = pk;   // adjacent e-slots (kp&7 even)
        }
        __syncthreads();
    }

    // ---- head: out[r] = sum_c h[r][c] w_head[c] + b_head ----
    float p = 0.0f;
    {
        const unsigned short* hf = hbuf[1];   // t=364: cur=0, wrote hbuf[1]
        const unsigned int hv = *(const unsigned int*)&hf[woff];
        p = bf2f((unsigned short)(hv & 0xffff)) * w_head[cw0]
          + bf2f((unsigned short)(hv >> 16))    * w_head[cw0 + 1];
    }
    p += __shfl_xor(p, 4);    // combine q-pairs
    p += __shfl_xor(p, 8);    // combine ct halves
    p += __shfl_xor(p, 16);   // combine l16 groups
    p += __shfl_xor(p, 32);
    if (lane < ROWS) red[wv][lane] = p;
    __syncthreads();
    if (tid < ROWS) {
        float s = b_head[0];
#pragma unroll
        for (int w = 0; w < NW; ++w) s += red[w][tid];
        out[rb + tid] = s;
    }
}

extern "C" void kernel_launch(void* const* d_in, const int* in_sizes, int n_in,
                              void* d_out, int out_size, void* d_ws, size_t ws_size,
                              hipStream_t stream)
{
    const float* x_dyn  = (const float*)d_in[0];
    const float* x_stat = (const float*)d_in[1];
    const float* w_i    = (const float*)d_in[2];
    const float* b_i    = (const float*)d_in[3];
    const float* w_f    = (const float*)d_in[4];
    const float* b_f    = (const float*)d_in[5];
    const float* w_g    = (const float*)d_in[6];
    const float* b_g    = (const float*)d_in[7];
    const float* w_o    = (const float*)d_in[8];
    const float* b_o    = (const float*)d_in[9];
    const float* w_head = (const float*)d_in[10];
    const float* b_head = (const float*)d_in[11];

    ealstm_fused<<<dim3(NBLK), dim3(512), 0, stream>>>(
        x_dyn, x_stat, w_i, b_i, w_f, b_f, w_g, b_g, w_o, b_o,
        w_head, b_head, (float*)d_out);
}